// Round 20
// baseline (114.204 us; speedup 1.0000x reference)
//
#include <hip/hip_runtime.h>

typedef unsigned long long u64;
typedef unsigned short u16;
typedef __bf16 bf16_t;
typedef bf16_t bf16x8 __attribute__((ext_vector_type(8)));
typedef float f32x4 __attribute__((ext_vector_type(4)));

#define DEVI __device__ __forceinline__

DEVI float gelu_f(float x) { return 0.5f * x * (1.0f + erff(x * 0.70710678f)); }

DEVI u16 f2bf(float x) {  // round-to-nearest-even f32 -> bf16
  unsigned u = __float_as_uint(x);
  return (u16)((u + 0x7fffu + ((u >> 16) & 1u)) >> 16);
}

DEVI void ce64(u64& a, u64& b) { u64 lo = a < b ? a : b; u64 hi = a < b ? b : a; a = lo; b = hi; }

DEVI u64 shflx64(u64 v, int m) {
  unsigned lo = (unsigned)__shfl_xor((int)(v & 0xffffffffull), m, 64);
  unsigned hi = (unsigned)__shfl_xor((int)(v >> 32), m, 64);
  return ((u64)hi << 32) | lo;
}

// t, o sorted ascending; t <- smallest 8 of union, sorted.
DEVI void take8(u64 t[8], const u64 o[8]) {
  u64 s[8];
#pragma unroll
  for (int i = 0; i < 8; ++i) { u64 x = o[7 - i]; s[i] = (t[i] < x) ? t[i] : x; }
  ce64(s[0], s[4]); ce64(s[1], s[5]); ce64(s[2], s[6]); ce64(s[3], s[7]);
  ce64(s[0], s[2]); ce64(s[1], s[3]); ce64(s[4], s[6]); ce64(s[5], s[7]);
  ce64(s[0], s[1]); ce64(s[2], s[3]); ce64(s[4], s[5]); ce64(s[6], s[7]);
#pragma unroll
  for (int i = 0; i < 8; ++i) t[i] = s[i];
}

DEVI void insert8(u64 t[8], u64 c) {
  if (c < t[7]) {
    t[7] = c;
    ce64(t[6], t[7]); ce64(t[5], t[6]); ce64(t[4], t[5]); ce64(t[3], t[4]);
    ce64(t[2], t[3]); ce64(t[1], t[2]); ce64(t[0], t[1]);
  }
}

// ================= fused preprocessing =================
// [0,392): key norms + bf16 keys (pad rows 100000..100351: knorm=+inf, kbf=0)
// [392,520): w2t   [520,1032): w3t   [1032,1288): w1ct   [1288,1544): cbf
// [1544,1560): w1kt   [1560]: zero padded ccnt (512*16 ints)
DEVI void wconv_body(float (*s)[33], const float* __restrict__ W, u16* __restrict__ Wt,
                     int K, int N, int bx, int by, int tid) {
  const int k0 = by * 32, n0 = bx * 32;
  const int a = tid >> 5, b2 = tid & 31;
#pragma unroll
  for (int p = 0; p < 4; ++p) s[a + p * 8][b2] = W[(size_t)(k0 + a + p * 8) * N + n0 + b2];
  __syncthreads();
#pragma unroll
  for (int p = 0; p < 4; ++p) Wt[(size_t)(n0 + a + p * 8) * K + k0 + b2] = f2bf(s[b2][a + p * 8]);
}

__global__ __launch_bounds__(256) void prep_kernel(const float* __restrict__ keys,
                                                   float* __restrict__ knorm,
                                                   u16* __restrict__ kbf,
                                                   const float* __restrict__ dw1,
                                                   u16* __restrict__ w1ct,
                                                   u16* __restrict__ w1kt,
                                                   const float* __restrict__ dw2,
                                                   u16* __restrict__ w2t,
                                                   const float* __restrict__ dw3,
                                                   u16* __restrict__ w3t,
                                                   const float* __restrict__ context,
                                                   u16* __restrict__ cbf,
                                                   int* __restrict__ ccnt) {
  __shared__ float s[32][33];
  const int b = blockIdx.x, tid = threadIdx.x;
  if (b < 392) {
    int j = b * 256 + tid;
    if (j < 100000) {
      const float4* kp = (const float4*)(keys + (size_t)j * 64);
      u16* op = kbf + (size_t)j * 64;
      float a0 = 0.f, a1 = 0.f;
#pragma unroll
      for (int u = 0; u < 16; u += 2) {
        float4 v0 = kp[u], v1 = kp[u + 1];
        a0 = fmaf(v0.x, v0.x, a0); a0 = fmaf(v0.y, v0.y, a0); a0 = fmaf(v0.z, v0.z, a0); a0 = fmaf(v0.w, v0.w, a0);
        a1 = fmaf(v1.x, v1.x, a1); a1 = fmaf(v1.y, v1.y, a1); a1 = fmaf(v1.z, v1.z, a1); a1 = fmaf(v1.w, v1.w, a1);
        ushort4 o0 = {f2bf(v0.x), f2bf(v0.y), f2bf(v0.z), f2bf(v0.w)};
        ushort4 o1 = {f2bf(v1.x), f2bf(v1.y), f2bf(v1.z), f2bf(v1.w)};
        *(ushort4*)(op + u * 4) = o0;
        *(ushort4*)(op + u * 4 + 4) = o1;
      }
      knorm[j] = a0 + a1;
    } else if (j < 100352) {  // pad: never selectable (s = +inf)
      knorm[j] = __uint_as_float(0x7f800000u);
      uint4 z = {0, 0, 0, 0};
      uint4* op = (uint4*)(kbf + (size_t)j * 64);
#pragma unroll
      for (int u = 0; u < 8; ++u) op[u] = z;
    }
  } else if (b < 520) {
    int r = b - 392;
    wconv_body(s, dw2, w2t, 256, 512, r & 15, r >> 4, tid);
  } else if (b < 1032) {
    int r = b - 520;
    wconv_body(s, dw3, w3t, 512, 1024, r & 31, r >> 5, tid);
  } else if (b < 1288) {
    int r = b - 1032;
    wconv_body(s, dw1 + (size_t)64 * 256, w1ct, 1024, 256, r & 7, r >> 3, tid);
  } else if (b < 1544) {
    int r = b - 1288;
    size_t idx = ((size_t)r * 256 + tid) * 8;
    float4 v0 = *(const float4*)(context + idx);
    float4 v1 = *(const float4*)(context + idx + 4);
    uint4 o;
    o.x = (unsigned)f2bf(v0.x) | ((unsigned)f2bf(v0.y) << 16);
    o.y = (unsigned)f2bf(v0.z) | ((unsigned)f2bf(v0.w) << 16);
    o.z = (unsigned)f2bf(v1.x) | ((unsigned)f2bf(v1.y) << 16);
    o.w = (unsigned)f2bf(v1.z) | ((unsigned)f2bf(v1.w) << 16);
    *(uint4*)(cbf + idx) = o;
  } else if (b < 1560) {
    int r = b - 1544;  // transpose dw1[0:64][256] -> w1kt[256][64]
    wconv_body(s, dw1, w1kt, 64, 256, r & 7, r >> 3, tid);
  } else {
    int4 z = {0, 0, 0, 0};
#pragma unroll
    for (int u = 0; u < 8; ++u) *(int4*)(ccnt + tid * 32 + u * 4) = z;  // 8192 ints
  }
}

// ================= encoder layer, split-K fp32, R=4 rows/block =================
// grid (COLS/64, 512/4), block 256 = 64 outputs x 4 k-slices. Each weight loaded ONCE
// and shared across 4 rows (L2 traffic /4); 4 independent fma chains per thread.
// Per-output fma order identical to r18 (single acc, k-ascending within slice).
template <int K, int COLS, int ACT, int QOUT>
__global__ __launch_bounds__(256) void encL_kernel(const float* __restrict__ A,
                                                   const float* __restrict__ W,
                                                   const float* __restrict__ bias,
                                                   float* __restrict__ out,
                                                   u16* __restrict__ qbf) {
  __shared__ float As[4][K];
  __shared__ float P[4][4][64];  // [row][slice][out]
  const int tid = threadIdx.x;
  const int row0 = blockIdx.y * 4;
  const int oi = tid & 63, ks = tid >> 6;
  const int col = blockIdx.x * 64 + oi;
  for (int i = tid; i < K; i += 256) {
    const int r = i / (K / 4), c4 = i % (K / 4);
    *(float4*)(&As[r][c4 * 4]) = *(const float4*)(A + (size_t)(row0 + r) * K + c4 * 4);
  }
  __syncthreads();
  const int k0 = ks * (K / 4);
  float acc[4] = {0.f, 0.f, 0.f, 0.f};
  for (int k4 = k0; k4 < k0 + K / 4; k4 += 4) {
    const float w0 = W[(size_t)(k4 + 0) * COLS + col];
    const float w1 = W[(size_t)(k4 + 1) * COLS + col];
    const float w2 = W[(size_t)(k4 + 2) * COLS + col];
    const float w3 = W[(size_t)(k4 + 3) * COLS + col];
#pragma unroll
    for (int r = 0; r < 4; ++r) {
      const float4 a = *(const float4*)(&As[r][k4]);
      acc[r] = fmaf(a.x, w0, acc[r]);
      acc[r] = fmaf(a.y, w1, acc[r]);
      acc[r] = fmaf(a.z, w2, acc[r]);
      acc[r] = fmaf(a.w, w3, acc[r]);
    }
  }
#pragma unroll
  for (int r = 0; r < 4; ++r) P[r][ks][oi] = acc[r];
  __syncthreads();
  // 256 threads = 4 rows x 64 outputs; deterministic fixed-order reduce
  {
    const int r = tid >> 6, o = tid & 63;
    const int c = blockIdx.x * 64 + o;
    float v = ((P[r][0][o] + P[r][1][o]) + P[r][2][o]) + P[r][3][o] + bias[c];
    if (ACT) v = gelu_f(v);
    out[(size_t)(row0 + r) * COLS + c] = v;
    if (QOUT) qbf[(size_t)(row0 + r) * COLS + c] = f2bf(v);
  }
}

// ================= bf16 MFMA GEMM, 64x64 tiles: C = act(A[M,K] @ Bt[N,K]^T + bias) =================
template <int ACT, int BIAS, int OUT_BF16>
__global__ __launch_bounds__(256) void mfma64_kernel(const u16* __restrict__ A,
                                                     const u16* __restrict__ Bt,
                                                     const float* __restrict__ bias,
                                                     void* __restrict__ Cout,
                                                     int M, int N, int K) {
  __shared__ u16 As[64 * 64];
  __shared__ u16 Bs[64 * 64];
  const int tid = threadIdx.x;
  const int wave = tid >> 6, lane = tid & 63;
  const int g = lane >> 4, li = lane & 15;
  const int wr = wave >> 1, wc = wave & 1;
  const int m0 = blockIdx.y * 64, n0 = blockIdx.x * 64;
  f32x4 acc[2][2];
  f32x4 zz = {0.f, 0.f, 0.f, 0.f};
#pragma unroll
  for (int i = 0; i < 2; ++i)
#pragma unroll
    for (int j = 0; j < 2; ++j) acc[i][j] = zz;

  const int o0 = tid * 16, o1 = o0 + 4096;
  const int r0s = o0 >> 7, s0 = (o0 >> 4) & 7;
  const int r1s = o1 >> 7, s1 = (o1 >> 4) & 7;
  const size_t a0off = (size_t)(m0 + r0s) * K + ((s0 ^ (r0s & 7)) << 3);
  const size_t a1off = (size_t)(m0 + r1s) * K + ((s1 ^ (r1s & 7)) << 3);
  const size_t b0off = (size_t)(n0 + r0s) * K + ((s0 ^ (r0s & 7)) << 3);
  const size_t b1off = (size_t)(n0 + r1s) * K + ((s1 ^ (r1s & 7)) << 3);

  for (int k0 = 0; k0 < K; k0 += 64) {
    uint4 ra0 = *(const uint4*)(A + a0off + k0);
    uint4 ra1 = *(const uint4*)(A + a1off + k0);
    uint4 rb0 = *(const uint4*)(Bt + b0off + k0);
    uint4 rb1 = *(const uint4*)(Bt + b1off + k0);
    __syncthreads();
    *(uint4*)((char*)As + o0) = ra0;
    *(uint4*)((char*)As + o1) = ra1;
    *(uint4*)((char*)Bs + o0) = rb0;
    *(uint4*)((char*)Bs + o1) = rb1;
    __syncthreads();
#pragma unroll
    for (int ko = 0; ko < 2; ++ko) {
      bf16x8 af[2], bfr[2];
#pragma unroll
      for (int mi = 0; mi < 2; ++mi) {
        const int row = wr * 32 + mi * 16 + li;
        const int sl = (ko * 4 + g) ^ (row & 7);
        af[mi] = *(const bf16x8*)((const char*)As + row * 128 + sl * 16);
      }
#pragma unroll
      for (int ni = 0; ni < 2; ++ni) {
        const int row = wc * 32 + ni * 16 + li;
        const int sl = (ko * 4 + g) ^ (row & 7);
        bfr[ni] = *(const bf16x8*)((const char*)Bs + row * 128 + sl * 16);
      }
#pragma unroll
      for (int mi = 0; mi < 2; ++mi)
#pragma unroll
        for (int ni = 0; ni < 2; ++ni)
          acc[mi][ni] = __builtin_amdgcn_mfma_f32_16x16x32_bf16(af[mi], bfr[ni], acc[mi][ni], 0, 0, 0);
    }
  }
#pragma unroll
  for (int ni = 0; ni < 2; ++ni) {
    const int col = n0 + wc * 32 + ni * 16 + li;
    const float bb = BIAS ? bias[col] : 0.f;
#pragma unroll
    for (int mi = 0; mi < 2; ++mi) {
#pragma unroll
      for (int r = 0; r < 4; ++r) {
        const int row = m0 + wr * 32 + mi * 16 + g * 4 + r;
        float v = acc[mi][ni][r] + bb;
        if (ACT) v = gelu_f(v);
        if (OUT_BF16) ((u16*)Cout)[(size_t)row * N + col] = f2bf(v);
        else ((float*)Cout)[(size_t)row * N + col] = v;
      }
    }
  }
}

// ================= dec3 + combine fused =================
__global__ __launch_bounds__(256) void dec3_combine_kernel(const u16* __restrict__ A,
                                                           const u16* __restrict__ Bt,
                                                           const float* __restrict__ bias,
                                                           const float* __restrict__ wtsb,
                                                           float* __restrict__ out,
                                                           int M, int N, int K) {
  __shared__ u16 As[64 * 64];
  __shared__ u16 Bs[64 * 64];
  const int tid = threadIdx.x;
  const int wave = tid >> 6, lane = tid & 63;
  const int g = lane >> 4, li = lane & 15;
  const int wr = wave >> 1, wc = wave & 1;
  const int m0 = blockIdx.y * 64, n0 = blockIdx.x * 64;
  f32x4 acc[2][2];
  f32x4 zz = {0.f, 0.f, 0.f, 0.f};
#pragma unroll
  for (int i = 0; i < 2; ++i)
#pragma unroll
    for (int j = 0; j < 2; ++j) acc[i][j] = zz;

  const int o0 = tid * 16, o1 = o0 + 4096;
  const int r0s = o0 >> 7, s0 = (o0 >> 4) & 7;
  const int r1s = o1 >> 7, s1 = (o1 >> 4) & 7;
  const size_t a0off = (size_t)(m0 + r0s) * K + ((s0 ^ (r0s & 7)) << 3);
  const size_t a1off = (size_t)(m0 + r1s) * K + ((s1 ^ (r1s & 7)) << 3);
  const size_t b0off = (size_t)(n0 + r0s) * K + ((s0 ^ (r0s & 7)) << 3);
  const size_t b1off = (size_t)(n0 + r1s) * K + ((s1 ^ (r1s & 7)) << 3);

  for (int k0 = 0; k0 < K; k0 += 64) {
    uint4 ra0 = *(const uint4*)(A + a0off + k0);
    uint4 ra1 = *(const uint4*)(A + a1off + k0);
    uint4 rb0 = *(const uint4*)(Bt + b0off + k0);
    uint4 rb1 = *(const uint4*)(Bt + b1off + k0);
    __syncthreads();
    *(uint4*)((char*)As + o0) = ra0;
    *(uint4*)((char*)As + o1) = ra1;
    *(uint4*)((char*)Bs + o0) = rb0;
    *(uint4*)((char*)Bs + o1) = rb1;
    __syncthreads();
#pragma unroll
    for (int ko = 0; ko < 2; ++ko) {
      bf16x8 af[2], bfr[2];
#pragma unroll
      for (int mi = 0; mi < 2; ++mi) {
        const int row = wr * 32 + mi * 16 + li;
        const int sl = (ko * 4 + g) ^ (row & 7);
        af[mi] = *(const bf16x8*)((const char*)As + row * 128 + sl * 16);
      }
#pragma unroll
      for (int ni = 0; ni < 2; ++ni) {
        const int row = wc * 32 + ni * 16 + li;
        const int sl = (ko * 4 + g) ^ (row & 7);
        bfr[ni] = *(const bf16x8*)((const char*)Bs + row * 128 + sl * 16);
      }
#pragma unroll
      for (int mi = 0; mi < 2; ++mi)
#pragma unroll
        for (int ni = 0; ni < 2; ++ni)
          acc[mi][ni] = __builtin_amdgcn_mfma_f32_16x16x32_bf16(af[mi], bfr[ni], acc[mi][ni], 0, 0, 0);
    }
  }
#pragma unroll
  for (int mi = 0; mi < 2; ++mi) {
    const int R16 = m0 + wr * 32 + mi * 16;
    const int qb = (R16 >> 3) + (g >> 1);
    const float4 wv = *(const float4*)(wtsb + qb * 8 + (g & 1) * 4);
#pragma unroll
    for (int ni = 0; ni < 2; ++ni) {
      const int col = n0 + wc * 32 + ni * 16 + li;
      const float bb = bias[col];
      float p = (acc[mi][ni][0] + bb) * wv.x;
      p = fmaf(acc[mi][ni][1] + bb, wv.y, p);
      p = fmaf(acc[mi][ni][2] + bb, wv.z, p);
      p = fmaf(acc[mi][ni][3] + bb, wv.w, p);
      p += __shfl_xor(p, 16, 64);
      if ((g & 1) == 0) out[(size_t)qb * 1024 + col] = p;
    }
  }
}

// ================= decoder layer 1, MFMA (fused gather) =================
__global__ __launch_bounds__(256) void dec1_mfma_kernel(const u16* __restrict__ kbf,
                                                        const int* __restrict__ idxb,
                                                        const float* __restrict__ h1c,
                                                        const u16* __restrict__ w1kt,
                                                        const float* __restrict__ db1,
                                                        u16* __restrict__ h1d) {
  __shared__ u16 As[64 * 64];
  __shared__ u16 Bs[64 * 64];
  const int tid = threadIdx.x;
  const int wave = tid >> 6, lane = tid & 63;
  const int g = lane >> 4, li = lane & 15;
  const int wr = wave >> 1, wc = wave & 1;
  const int r0 = blockIdx.y * 64, c0 = blockIdx.x * 64;
  {
    const int o0 = tid * 16, o1 = o0 + 4096;
    const int ra = o0 >> 7, sa = (o0 >> 4) & 7;
    const int rb = o1 >> 7, sb = (o1 >> 4) & 7;
    const int ia = idxb[r0 + ra], ib = idxb[r0 + rb];
    uint4 va = *(const uint4*)(kbf + (size_t)ia * 64 + ((sa ^ (ra & 7)) << 3));
    uint4 vb = *(const uint4*)(kbf + (size_t)ib * 64 + ((sb ^ (rb & 7)) << 3));
    uint4 wa = *(const uint4*)(w1kt + (size_t)(c0 + ra) * 64 + ((sa ^ (ra & 7)) << 3));
    uint4 wb = *(const uint4*)(w1kt + (size_t)(c0 + rb) * 64 + ((sb ^ (rb & 7)) << 3));
    *(uint4*)((char*)As + o0) = va;
    *(uint4*)((char*)As + o1) = vb;
    *(uint4*)((char*)Bs + o0) = wa;
    *(uint4*)((char*)Bs + o1) = wb;
  }
  __syncthreads();
  f32x4 acc[2][2];
  f32x4 zz = {0.f, 0.f, 0.f, 0.f};
#pragma unroll
  for (int i = 0; i < 2; ++i)
#pragma unroll
    for (int j = 0; j < 2; ++j) acc[i][j] = zz;
#pragma unroll
  for (int ko = 0; ko < 2; ++ko) {
    bf16x8 af[2], bfr[2];
#pragma unroll
    for (int mi = 0; mi < 2; ++mi) {
      const int row = wr * 32 + mi * 16 + li;
      const int sl = (ko * 4 + g) ^ (row & 7);
      af[mi] = *(const bf16x8*)((const char*)As + row * 128 + sl * 16);
    }
#pragma unroll
    for (int ni = 0; ni < 2; ++ni) {
      const int row = wc * 32 + ni * 16 + li;
      const int sl = (ko * 4 + g) ^ (row & 7);
      bfr[ni] = *(const bf16x8*)((const char*)Bs + row * 128 + sl * 16);
    }
#pragma unroll
    for (int mi = 0; mi < 2; ++mi)
#pragma unroll
      for (int ni = 0; ni < 2; ++ni)
        acc[mi][ni] = __builtin_amdgcn_mfma_f32_16x16x32_bf16(af[mi], bfr[ni], acc[mi][ni], 0, 0, 0);
  }
#pragma unroll
  for (int ni = 0; ni < 2; ++ni) {
    const int col = c0 + wc * 32 + ni * 16 + li;
    const float bb = db1[col];
#pragma unroll
    for (int mi = 0; mi < 2; ++mi) {
      const int rowb = r0 + wr * 32 + mi * 16 + g * 4;
      const float hv = h1c[(size_t)(rowb >> 3) * 256 + col];
#pragma unroll
      for (int r = 0; r < 4; ++r) {
        float v = acc[mi][ni][r] + hv + bb;
        h1d[(size_t)(rowb + r) * 256 + col] = f2bf(gelu_f(v));
      }
    }
  }
}

// ================= pass A: per-(chunk, query) min; K-fragments hoisted to registers =================
// grid 392 (chunk), block 256 = 4 waves; wave's 32 ds_read_b128 done ONCE (not per q-group).
__global__ __launch_bounds__(256) void passA_kernel(const u16* __restrict__ qbf,
                                                    const u16* __restrict__ kbf,
                                                    const float* __restrict__ knorm,
                                                    float* __restrict__ cminT,
                                                    float* __restrict__ cminR) {
  __shared__ u16 Ks[256 * 64];  // 32 KB, XOR-swizzled
  __shared__ float Kn[256];
  const int c = blockIdx.x;
  const int tid = threadIdx.x, wave = tid >> 6, lane = tid & 63;
  const int g = lane >> 4, qi = lane & 15;
#pragma unroll
  for (int r = 0; r < 8; ++r) {
    const int o = tid * 16 + r * 4096;
    const int row = o >> 7, sl = (o >> 4) & 7;
    *(uint4*)((char*)Ks + o) =
        *(const uint4*)(kbf + ((size_t)c * 256 + row) * 64 + ((sl ^ (row & 7)) << 3));
  }
  if (tid < 64) *(float4*)(Kn + tid * 4) = *(const float4*)(knorm + c * 256 + tid * 4);
  __syncthreads();
  const int sl0 = (g ^ (qi & 7)) * 16, sl1 = ((g + 4) ^ (qi & 7)) * 16;
  // hoist this lane's K fragments (invariant across q-groups)
  bf16x8 ka[16], kb[16];
#pragma unroll
  for (int t = 0; t < 16; ++t) {
    const int rb = (t * 16 + qi) * 128;
    ka[t] = *(const bf16x8*)((const char*)Ks + rb + sl0);
    kb[t] = *(const bf16x8*)((const char*)Ks + rb + sl1);
  }
  for (int it = 0; it < 8; ++it) {
    const int q = (wave * 8 + it) * 16 + qi;
    const bf16x8 b0 = *(const bf16x8*)(qbf + (size_t)q * 64 + g * 8);
    const bf16x8 b1 = *(const bf16x8*)(qbf + (size_t)q * 64 + 32 + g * 8);
    float m = 3.4e38f;
#pragma unroll
    for (int t = 0; t < 16; ++t) {
      f32x4 zz = {0.f, 0.f, 0.f, 0.f};
      f32x4 acc = __builtin_amdgcn_mfma_f32_16x16x32_bf16(ka[t], b0, zz, 0, 0, 0);
      acc = __builtin_amdgcn_mfma_f32_16x16x32_bf16(kb[t], b1, acc, 0, 0, 0);
      const float4 kn = *(const float4*)(&Kn[t * 16 + g * 4]);
      m = fminf(m, fmaf(-2.f, acc[0], kn.x));
      m = fminf(m, fmaf(-2.f, acc[1], kn.y));
      m = fminf(m, fmaf(-2.f, acc[2], kn.z));
      m = fminf(m, fmaf(-2.f, acc[3], kn.w));
    }
    m = fminf(m, __shfl_xor(m, 16, 64));
    m = fminf(m, __shfl_xor(m, 32, 64));
    if (lane < 16) {
      cminT[(size_t)c * 512 + q] = m;
      cminR[(size_t)q * 392 + c] = m;
    }
  }
}

// ================= tau: per query, 8th-smallest chunk-min + margin =================
__global__ __launch_bounds__(256) void tau_kernel(const float* __restrict__ cminR,
                                                  float* __restrict__ tau) {
  const int wave = threadIdx.x >> 6, lane = threadIdx.x & 63;
  const int q = blockIdx.x * 4 + wave;
  const float* cp = cminR + (size_t)q * 392;
  u64 t[8];
#pragma unroll
  for (int i = 0; i < 8; ++i) t[i] = ~0ull;
  for (int i = lane; i < 392; i += 64)
    insert8(t, ((u64)__float_as_uint(cp[i]) << 32) | (unsigned)i);
#pragma unroll
  for (int m = 1; m < 64; m <<= 1) {
    u64 o[8];
#pragma unroll
    for (int i = 0; i < 8; ++i) o[i] = shflx64(t[i], m);
    take8(t, o);
  }
  if (lane == 0)
    tau[q] = __uint_as_float((unsigned)(t[7] >> 32)) + 0.02f;  // >= exact-d8 (bf16 err ~2e-3 << 0.02)
}

// ================= pass B: (chunk, 64-query slice); early-exit before staging =================
__global__ __launch_bounds__(256) void passB_kernel(const u16* __restrict__ qbf,
                                                    const u16* __restrict__ kbf,
                                                    const float* __restrict__ knorm,
                                                    const float* __restrict__ cminT,
                                                    const float* __restrict__ tau,
                                                    int* __restrict__ ccnt,
                                                    int* __restrict__ clist) {
  __shared__ u16 Ks[256 * 64];        // 32 KB
  __shared__ float Kn[256];
  __shared__ unsigned short qlist[64];
  __shared__ unsigned acc_pk[4096];   // 16 KB accept staging
  __shared__ int nql, acc_n;
  const int c = blockIdx.x;
  const int qs0 = blockIdx.y * 64;
  const int tid = threadIdx.x, wave = tid >> 6, lane = tid & 63;
  const int g = lane >> 4, qi = lane & 15;
  if (tid == 0) { nql = 0; acc_n = 0; }
  __syncthreads();
  if (tid < 64) {
    const int q = qs0 + tid;
    if (cminT[(size_t)c * 512 + q] <= tau[q]) {  // coalesced 64-float qualify read
      int p = atomicAdd(&nql, 1);
      qlist[p] = (unsigned short)q;
    }
  }
  __syncthreads();
  const int nq = nql;
  if (nq == 0) return;  // uniform: skip staging entirely
#pragma unroll
  for (int r = 0; r < 8; ++r) {
    const int o = tid * 16 + r * 4096;
    const int row = o >> 7, sl = (o >> 4) & 7;
    *(uint4*)((char*)Ks + o) =
        *(const uint4*)(kbf + ((size_t)c * 256 + row) * 64 + ((sl ^ (row & 7)) << 3));
  }
  if (tid < 64) *(float4*)(Kn + tid * 4) = *(const float4*)(knorm + c * 256 + tid * 4);
  __syncthreads();
  const int sl0 = (g ^ (qi & 7)) * 16, sl1 = ((g + 4) ^ (qi & 7)) * 16;
  const float NINF = __uint_as_float(0xff800000u);
  for (int grp = wave; grp * 16 < nq; grp += 4) {
    const int qx = grp * 16 + qi;
    const int valid = qx < nq;
    const int q = valid ? (int)qlist[qx] : 0;
    const float thr = valid ? tau[q] : NINF;
    const bf16x8 b0 = *(const bf16x8*)(qbf + (size_t)q * 64 + g * 8);
    const bf16x8 b1 = *(const bf16x8*)(qbf + (size_t)q * 64 + 32 + g * 8);
#pragma unroll
    for (int t = 0; t < 16; ++t) {
      const int rb = (t * 16 + qi) * 128;
      bf16x8 a0 = *(const bf16x8*)((const char*)Ks + rb + sl0);
      bf16x8 a1 = *(const bf16x8*)((const char*)Ks + rb + sl1);
      f32x4 zz = {0.f, 0.f, 0.f, 0.f};
      f32x4 acc = __builtin_amdgcn_mfma_f32_16x16x32_bf16(a0, b0, zz, 0, 0, 0);
      acc = __builtin_amdgcn_mfma_f32_16x16x32_bf16(a1, b1, acc, 0, 0, 0);
#pragma unroll
      for (int r = 0; r < 4; ++r) {
        const float s = fmaf(-2.f, acc[r], Kn[t * 16 + g * 4 + r]);
        if (s <= thr) {  // LDS-stage the accept
          int p = atomicAdd(&acc_n, 1);
          if (p < 4096) {
            acc_pk[p] = ((unsigned)q << 17) | (unsigned)(c * 256 + t * 16 + g * 4 + r);
          } else {  // overflow fallback: direct, correct
            int pos = atomicAdd(&ccnt[q * 16], 1);
            if (pos < 128) clist[q * 128 + pos] = c * 256 + t * 16 + g * 4 + r;
          }
        }
      }
    }
  }
  __syncthreads();
  int na = acc_n;
  if (na > 4096) na = 4096;
  for (int i = tid; i < na; i += 256) {
    const unsigned pk = acc_pk[i];
    const int q = (int)(pk >> 17);
    const int key = (int)(pk & 0x1FFFFu);
    int pos = atomicAdd(&ccnt[q * 16], 1);
    if (pos < 128) clist[q * 128 + pos] = key;
  }
}

// ================= exact fp32 re-rank of survivors -> final top-8 =================
__global__ __launch_bounds__(256) void rerank_kernel(const int* __restrict__ clist,
                                                     const int* __restrict__ ccnt,
                                                     const float* __restrict__ qc,
                                                     const float* __restrict__ keys,
                                                     const float* __restrict__ knorm,
                                                     int* __restrict__ idxb,
                                                     float* __restrict__ wtsb,
                                                     float* __restrict__ conf) {
  const int sub = threadIdx.x >> 6, lane = threadIdx.x & 63;
  const int q = blockIdx.x * 4 + sub;
  __shared__ float qs[4][64];
  if (lane < 16) *(float4*)(&qs[sub][lane * 4]) = ((const float4*)(qc + (size_t)q * 64))[lane];
  __syncthreads();
  float qn = 0.f;
#pragma unroll
  for (int u = 0; u < 16; ++u) {
    float4 v = *(const float4*)(&qs[sub][u * 4]);
    qn = fmaf(v.x, v.x, fmaf(v.y, v.y, fmaf(v.z, v.z, fmaf(v.w, v.w, qn))));
  }
  int n = ccnt[q * 16];
  if (n > 128) n = 128;
  u64 t[8];
#pragma unroll
  for (int i = 0; i < 8; ++i) t[i] = ~0ull;
  for (int ci = lane; ci < n; ci += 64) {
    const int idx = clist[q * 128 + ci];
    const float4* kr = (const float4*)(keys + (size_t)idx * 64);
    float a0 = 0.f, a1 = 0.f, a2 = 0.f, a3 = 0.f;
#pragma unroll
    for (int u = 0; u < 16; u += 4) {
      float4 k0 = kr[u], k1 = kr[u + 1], k2 = kr[u + 2], k3 = kr[u + 3];
      float4 q0 = *(const float4*)(&qs[sub][u * 4]), q1 = *(const float4*)(&qs[sub][u * 4 + 4]);
      float4 q2 = *(const float4*)(&qs[sub][u * 4 + 8]), q3 = *(const float4*)(&qs[sub][u * 4 + 12]);
      a0 = fmaf(q0.x, k0.x, a0); a0 = fmaf(q0.y, k0.y, a0); a0 = fmaf(q0.z, k0.z, a0); a0 = fmaf(q0.w, k0.w, a0);
      a1 = fmaf(q1.x, k1.x, a1); a1 = fmaf(q1.y, k1.y, a1); a1 = fmaf(q1.z, k1.z, a1); a1 = fmaf(q1.w, k1.w, a1);
      a2 = fmaf(q2.x, k2.x, a2); a2 = fmaf(q2.y, k2.y, a2); a2 = fmaf(q2.z, k2.z, a2); a2 = fmaf(q2.w, k2.w, a2);
      a3 = fmaf(q3.x, k3.x, a3); a3 = fmaf(q3.y, k3.y, a3); a3 = fmaf(q3.z, k3.z, a3); a3 = fmaf(q3.w, k3.w, a3);
    }
    float dot = (a0 + a1) + (a2 + a3);
    float d2 = fmaf(-2.f, dot, qn + knorm[idx]);
    d2 = fmaxf(d2, 0.f);
    insert8(t, ((u64)__float_as_uint(d2) << 32) | (unsigned)idx);
  }
#pragma unroll
  for (int m = 1; m < 64; m <<= 1) {
    u64 o[8];
#pragma unroll
    for (int i = 0; i < 8; ++i) o[i] = shflx64(t[i], m);
    take8(t, o);
  }
  if (lane == 0) {
    float w8[8], s = 0.f;
#pragma unroll
    for (int i = 0; i < 8; ++i) {
      float d = __uint_as_float((unsigned)(t[i] >> 32));
      w8[i] = 1.f / (d + 1e-6f);
      s += w8[i];
    }
    conf[q] = w8[0];
#pragma unroll
    for (int i = 0; i < 8; ++i) {
      idxb[q * 8 + i] = (int)(unsigned)(t[i] & 0xffffffffull);
      wtsb[q * 8 + i] = w8[i] / s;
    }
  }
}

extern "C" void kernel_launch(void* const* d_in, const int* in_sizes, int n_in,
                              void* d_out, int out_size, void* d_ws, size_t ws_size,
                              hipStream_t stream) {
  const float* query   = (const float*)d_in[0];
  const float* context = (const float*)d_in[1];
  const float* keys    = (const float*)d_in[2];
  const float* ew1 = (const float*)d_in[3];
  const float* eb1 = (const float*)d_in[4];
  const float* ew2 = (const float*)d_in[5];
  const float* eb2 = (const float*)d_in[6];
  const float* ew3 = (const float*)d_in[7];
  const float* eb3 = (const float*)d_in[8];
  const float* dw1 = (const float*)d_in[9];
  const float* db1 = (const float*)d_in[10];
  const float* dw2 = (const float*)d_in[11];
  const float* db2 = (const float*)d_in[12];
  const float* dw3 = (const float*)d_in[13];
  const float* db3 = (const float*)d_in[14];
  float* out = (float*)d_out;

  char* ws = (char*)d_ws;
  float* qc    = (float*)(ws + 0);          // 131072
  float* knorm = (float*)(ws + 131072);     // 100352*4 = 401408
  u16*   qbf   = (u16*)  (ws + 532480);     // 65536
  int*   idxb  = (int*)  (ws + 1384448);    // 16384
  float* wtsb  = (float*)(ws + 1400832);    // 16384
  float* h1c   = (float*)(ws + 1417216);    // 524288
  u16*   kbf   = (u16*)  (ws + 1941504);    // 100352*64*2 = 12845056
  float* cminT = (float*)(ws + 14786560);   // 392*512*4 = 802816
  float* cminR = (float*)(ws + 15589376);   // 512*392*4 = 802816
  float* tau   = (float*)(ws + 16392192);   // 2048
  int*   ccnt  = (int*)  (ws + 16394240);   // 512*16*4 = 32768 (64B-padded counters)
  int*   clist = (int*)  (ws + 16427008);   // 512*128*4 = 262144
  u16*   h1d   = (u16*)  (ws + 16689152);   // 2097152
  u16*   h2d   = (u16*)  (ws + 18786304);   // 4194304
  u16*   w2t   = (u16*)  (ws + 22980608);   // 262144
  u16*   w3t   = (u16*)  (ws + 23242752);   // 1048576
  u16*   w1ct  = (u16*)  (ws + 24291328);   // 524288
  u16*   cbf   = (u16*)  (ws + 24815616);   // 1048576
  u16*   w1kt  = (u16*)  (ws + 25864192);   // 32768
  float* eh1f  = (float*)(ws + 25896960);   // 512*256*4 = 524288
  float* eh2f  = (float*)(ws + 26421248);   // 512*128*4 = 262144 (end 26683392)

  // fused preprocessing
  prep_kernel<<<dim3(1561), dim3(256), 0, stream>>>(keys, knorm, kbf, dw1, w1ct, w1kt,
                                                    dw2, w2t, dw3, w3t, context, cbf, ccnt);

  // encoder: split-K fp32 layers, 4 rows/block (bit-identical reduce order; emits qc+qbf)
  encL_kernel<1024, 256, 1, 0><<<dim3(4, 128), dim3(256), 0, stream>>>(query, ew1, eb1, eh1f, nullptr);
  encL_kernel<256, 128, 1, 0><<<dim3(2, 128), dim3(256), 0, stream>>>(eh1f, ew2, eb2, eh2f, nullptr);
  encL_kernel<128, 64, 0, 1><<<dim3(1, 128), dim3(256), 0, stream>>>(eh2f, ew3, eb3, qc, qbf);

  // shared context part of decoder layer 1
  mfma64_kernel<0, 0, 0><<<dim3(4, 8), dim3(256), 0, stream>>>(cbf, w1ct, nullptr, h1c,
                                                               512, 256, 1024);

  // selection: LDS-staged chunk-min scan -> tau -> sliced filtered collect -> exact rerank
  passA_kernel<<<dim3(392), dim3(256), 0, stream>>>(qbf, kbf, knorm, cminT, cminR);
  tau_kernel<<<dim3(128), dim3(256), 0, stream>>>(cminR, tau);
  passB_kernel<<<dim3(392, 8), dim3(256), 0, stream>>>(qbf, kbf, knorm, cminT, tau, ccnt, clist);
  rerank_kernel<<<dim3(128), dim3(256), 0, stream>>>(clist, ccnt, qc, keys, knorm,
                                                     idxb, wtsb, out + 524288);

  // decoder
  dec1_mfma_kernel<<<dim3(4, 64), dim3(256), 0, stream>>>(kbf, idxb, h1c, w1kt, db1, h1d);
  mfma64_kernel<1, 1, 1><<<dim3(8, 64), dim3(256), 0, stream>>>(h1d, w2t, db2, h2d, 4096, 512, 256);
  dec3_combine_kernel<<<dim3(16, 64), dim3(256), 0, stream>>>(h2d, w3t, db3, wtsb, out,
                                                              4096, 1024, 512);
}

// Round 21
// 102.735 us; speedup vs baseline: 1.1116x; 1.1116x over previous
//
#include <hip/hip_runtime.h>

typedef unsigned long long u64;
typedef unsigned short u16;
typedef __bf16 bf16_t;
typedef bf16_t bf16x8 __attribute__((ext_vector_type(8)));
typedef float f32x4 __attribute__((ext_vector_type(4)));

#define DEVI __device__ __forceinline__

DEVI float gelu_f(float x) { return 0.5f * x * (1.0f + erff(x * 0.70710678f)); }

DEVI u16 f2bf(float x) {  // round-to-nearest-even f32 -> bf16
  unsigned u = __float_as_uint(x);
  return (u16)((u + 0x7fffu + ((u >> 16) & 1u)) >> 16);
}

DEVI void ce64(u64& a, u64& b) { u64 lo = a < b ? a : b; u64 hi = a < b ? b : a; a = lo; b = hi; }

DEVI u64 shflx64(u64 v, int m) {
  unsigned lo = (unsigned)__shfl_xor((int)(v & 0xffffffffull), m, 64);
  unsigned hi = (unsigned)__shfl_xor((int)(v >> 32), m, 64);
  return ((u64)hi << 32) | lo;
}

// t, o sorted ascending; t <- smallest 8 of union, sorted.
DEVI void take8(u64 t[8], const u64 o[8]) {
  u64 s[8];
#pragma unroll
  for (int i = 0; i < 8; ++i) { u64 x = o[7 - i]; s[i] = (t[i] < x) ? t[i] : x; }
  ce64(s[0], s[4]); ce64(s[1], s[5]); ce64(s[2], s[6]); ce64(s[3], s[7]);
  ce64(s[0], s[2]); ce64(s[1], s[3]); ce64(s[4], s[6]); ce64(s[5], s[7]);
  ce64(s[0], s[1]); ce64(s[2], s[3]); ce64(s[4], s[5]); ce64(s[6], s[7]);
#pragma unroll
  for (int i = 0; i < 8; ++i) t[i] = s[i];
}

DEVI void insert8(u64 t[8], u64 c) {
  if (c < t[7]) {
    t[7] = c;
    ce64(t[6], t[7]); ce64(t[5], t[6]); ce64(t[4], t[5]); ce64(t[3], t[4]);
    ce64(t[2], t[3]); ce64(t[1], t[2]); ce64(t[0], t[1]);
  }
}

// ================= fused preprocessing + independent GEMMs =================
// [0,392): key norms + bf16 keys (pad rows: knorm=+inf, kbf=0)
// [392,520): w2t   [520,1032): w3t   [1032,1048): w1kt   [1048]: zero ccnt
// [1049,1561): h1c = context @ dw1[64:,:]  (fp32, R=4 split-K)
// [1561,2073): enc1 = gelu(query @ ew1 + eb1) (fp32, R=4 split-K; bit-identical to r20)
DEVI void wconv_body(float (*s)[33], const float* __restrict__ W, u16* __restrict__ Wt,
                     int K, int N, int bx, int by, int tid) {
  const int k0 = by * 32, n0 = bx * 32;
  const int a = tid >> 5, b2 = tid & 31;
#pragma unroll
  for (int p = 0; p < 4; ++p) s[a + p * 8][b2] = W[(size_t)(k0 + a + p * 8) * N + n0 + b2];
  __syncthreads();
#pragma unroll
  for (int p = 0; p < 4; ++p) Wt[(size_t)(n0 + a + p * 8) * K + k0 + b2] = f2bf(s[b2][a + p * 8]);
}

// R=4 split-K fp32 GEMM body, K=1024 -> 256 cols (bit-identical order to r20 encL)
template <int ACT, int HASB>
DEVI void gemmR4_body(float (*hAs)[1024], float (*hP)[4][64],
                      const float* __restrict__ A, const float* __restrict__ W,
                      const float* __restrict__ bias, float* __restrict__ out,
                      int r, int tid) {
  const int bx = r & 3, by = r >> 2;
  const int row0 = by * 4;
  const int oi = tid & 63, ks = tid >> 6;
  const int col = bx * 64 + oi;
  for (int i = tid; i < 1024; i += 256) {
    const int rr = i >> 8, c4 = i & 255;
    *(float4*)(&hAs[rr][c4 * 4]) = *(const float4*)(A + (size_t)(row0 + rr) * 1024 + c4 * 4);
  }
  __syncthreads();
  const int k0 = ks * 256;
  float acc[4] = {0.f, 0.f, 0.f, 0.f};
  for (int k4 = k0; k4 < k0 + 256; k4 += 4) {
    const float w0 = W[(size_t)(k4 + 0) * 256 + col];
    const float w1 = W[(size_t)(k4 + 1) * 256 + col];
    const float w2 = W[(size_t)(k4 + 2) * 256 + col];
    const float w3 = W[(size_t)(k4 + 3) * 256 + col];
#pragma unroll
    for (int rr = 0; rr < 4; ++rr) {
      const float4 a = *(const float4*)(&hAs[rr][k4]);
      acc[rr] = fmaf(a.x, w0, acc[rr]);
      acc[rr] = fmaf(a.y, w1, acc[rr]);
      acc[rr] = fmaf(a.z, w2, acc[rr]);
      acc[rr] = fmaf(a.w, w3, acc[rr]);
    }
  }
#pragma unroll
  for (int rr = 0; rr < 4; ++rr) hP[rr][ks][oi] = acc[rr];
  __syncthreads();
  {
    const int rr = tid >> 6, o = tid & 63;
    const int c = bx * 64 + o;
    float v = ((hP[rr][0][o] + hP[rr][1][o]) + hP[rr][2][o]) + hP[rr][3][o] +
              (HASB ? bias[c] : 0.f);
    if (ACT) v = gelu_f(v);
    out[(size_t)(row0 + rr) * 256 + c] = v;
  }
}

__global__ __launch_bounds__(256) void prep_kernel(const float* __restrict__ keys,
                                                   float* __restrict__ knorm,
                                                   u16* __restrict__ kbf,
                                                   const float* __restrict__ dw1,
                                                   u16* __restrict__ w1kt,
                                                   const float* __restrict__ dw2,
                                                   u16* __restrict__ w2t,
                                                   const float* __restrict__ dw3,
                                                   u16* __restrict__ w3t,
                                                   const float* __restrict__ context,
                                                   float* __restrict__ h1c,
                                                   int* __restrict__ ccnt,
                                                   const float* __restrict__ query,
                                                   const float* __restrict__ ew1,
                                                   const float* __restrict__ eb1,
                                                   float* __restrict__ eh1f) {
  __shared__ float s[32][33];
  __shared__ float hAs[4][1024];
  __shared__ float hP[4][4][64];
  const int b = blockIdx.x, tid = threadIdx.x;
  if (b < 392) {
    int j = b * 256 + tid;
    if (j < 100000) {
      const float4* kp = (const float4*)(keys + (size_t)j * 64);
      u16* op = kbf + (size_t)j * 64;
      float a0 = 0.f, a1 = 0.f;
#pragma unroll
      for (int u = 0; u < 16; u += 2) {
        float4 v0 = kp[u], v1 = kp[u + 1];
        a0 = fmaf(v0.x, v0.x, a0); a0 = fmaf(v0.y, v0.y, a0); a0 = fmaf(v0.z, v0.z, a0); a0 = fmaf(v0.w, v0.w, a0);
        a1 = fmaf(v1.x, v1.x, a1); a1 = fmaf(v1.y, v1.y, a1); a1 = fmaf(v1.z, v1.z, a1); a1 = fmaf(v1.w, v1.w, a1);
        ushort4 o0 = {f2bf(v0.x), f2bf(v0.y), f2bf(v0.z), f2bf(v0.w)};
        ushort4 o1 = {f2bf(v1.x), f2bf(v1.y), f2bf(v1.z), f2bf(v1.w)};
        *(ushort4*)(op + u * 4) = o0;
        *(ushort4*)(op + u * 4 + 4) = o1;
      }
      knorm[j] = a0 + a1;
    } else if (j < 100352) {  // pad: never selectable (s = +inf)
      knorm[j] = __uint_as_float(0x7f800000u);
      uint4 z = {0, 0, 0, 0};
      uint4* op = (uint4*)(kbf + (size_t)j * 64);
#pragma unroll
      for (int u = 0; u < 8; ++u) op[u] = z;
    }
  } else if (b < 520) {
    int r = b - 392;
    wconv_body(s, dw2, w2t, 256, 512, r & 15, r >> 4, tid);
  } else if (b < 1032) {
    int r = b - 520;
    wconv_body(s, dw3, w3t, 512, 1024, r & 31, r >> 5, tid);
  } else if (b < 1048) {
    int r = b - 1032;  // transpose dw1[0:64][256] -> w1kt[256][64]
    wconv_body(s, dw1, w1kt, 64, 256, r & 7, r >> 3, tid);
  } else if (b == 1048) {
    int4 z = {0, 0, 0, 0};
#pragma unroll
    for (int u = 0; u < 8; ++u) *(int4*)(ccnt + tid * 32 + u * 4) = z;  // 8192 ints
  } else if (b < 1561) {
    // h1c = context @ dw1[64:,:] (fp32; decode path only, more accurate than prior bf16)
    gemmR4_body<0, 0>(hAs, hP, context, dw1 + (size_t)64 * 256, nullptr, h1c, b - 1049, tid);
  } else {
    // enc1 (bit-identical to r20 encL<1024,256,1,0>)
    gemmR4_body<1, 1>(hAs, hP, query, ew1, eb1, eh1f, b - 1561, tid);
  }
}

// ================= enc2+enc3 fused (bit-identical slice splits/reduce order) =================
// grid 128, block 512; block = 4 rows. L2: 128 cols x 4 slices of 64; L3: 64 cols x 4 slices of 32.
__global__ __launch_bounds__(512) void enc23_kernel(const float* __restrict__ eh1f,
                                                    const float* __restrict__ ew2,
                                                    const float* __restrict__ eb2,
                                                    const float* __restrict__ ew3,
                                                    const float* __restrict__ eb3,
                                                    float* __restrict__ qc,
                                                    u16* __restrict__ qbf) {
  __shared__ float As[4][256];
  __shared__ float P2[4][4][128];
  __shared__ float H2[4][128];
  __shared__ float P3[4][4][64];
  const int tid = threadIdx.x;
  const int row0 = blockIdx.x * 4;
  for (int i = tid; i < 256; i += 512) {  // 4 rows x 64 float4
    const int r = i >> 6, c4 = i & 63;
    *(float4*)(&As[r][c4 * 4]) = *(const float4*)(eh1f + (size_t)(row0 + r) * 256 + c4 * 4);
  }
  __syncthreads();
  {  // layer 2: col = tid&127, ks = tid>>7 (4 slices of 64)
    const int col = tid & 127, ks = tid >> 7;
    const int k0 = ks * 64;
    float acc[4] = {0.f, 0.f, 0.f, 0.f};
    for (int k4 = k0; k4 < k0 + 64; k4 += 4) {
      const float w0 = ew2[(size_t)(k4 + 0) * 128 + col];
      const float w1 = ew2[(size_t)(k4 + 1) * 128 + col];
      const float w2 = ew2[(size_t)(k4 + 2) * 128 + col];
      const float w3 = ew2[(size_t)(k4 + 3) * 128 + col];
#pragma unroll
      for (int r = 0; r < 4; ++r) {
        const float4 a = *(const float4*)(&As[r][k4]);
        acc[r] = fmaf(a.x, w0, acc[r]);
        acc[r] = fmaf(a.y, w1, acc[r]);
        acc[r] = fmaf(a.z, w2, acc[r]);
        acc[r] = fmaf(a.w, w3, acc[r]);
      }
    }
#pragma unroll
    for (int r = 0; r < 4; ++r) P2[r][ks][col] = acc[r];
  }
  __syncthreads();
  {  // layer-2 reduce: 512 thr = 4 rows x 128 cols
    const int r = tid >> 7, o = tid & 127;
    float v = ((P2[r][0][o] + P2[r][1][o]) + P2[r][2][o]) + P2[r][3][o] + eb2[o];
    H2[r][o] = gelu_f(v);
  }
  __syncthreads();
  {  // layer 3: col = tid&63, ks = (tid>>6)&3 (4 slices of 32), half = tid>>8 -> rows {2h, 2h+1}
    const int col = tid & 63, ks = (tid >> 6) & 3, half = tid >> 8;
    const int k0 = ks * 32;
#pragma unroll
    for (int j = 0; j < 2; ++j) {
      const int r = half * 2 + j;
      float a0 = 0.f;
      for (int k4 = k0; k4 < k0 + 32; k4 += 4) {
        const float4 a = *(const float4*)(&H2[r][k4]);
        a0 = fmaf(a.x, ew3[(size_t)(k4 + 0) * 64 + col], a0);
        a0 = fmaf(a.y, ew3[(size_t)(k4 + 1) * 64 + col], a0);
        a0 = fmaf(a.z, ew3[(size_t)(k4 + 2) * 64 + col], a0);
        a0 = fmaf(a.w, ew3[(size_t)(k4 + 3) * 64 + col], a0);
      }
      P3[r][ks][col] = a0;
    }
  }
  __syncthreads();
  if (tid < 256) {  // layer-3 reduce: 4 rows x 64 cols; no act; emit qc + qbf
    const int r = tid >> 6, o = tid & 63;
    float v = ((P3[r][0][o] + P3[r][1][o]) + P3[r][2][o]) + P3[r][3][o] + eb3[o];
    qc[(size_t)(row0 + r) * 64 + o] = v;
    qbf[(size_t)(row0 + r) * 64 + o] = f2bf(v);
  }
}

// ================= bf16 MFMA GEMM, 64x64 tiles: C = act(A[M,K] @ Bt[N,K]^T + bias) =================
template <int ACT, int BIAS, int OUT_BF16>
__global__ __launch_bounds__(256) void mfma64_kernel(const u16* __restrict__ A,
                                                     const u16* __restrict__ Bt,
                                                     const float* __restrict__ bias,
                                                     void* __restrict__ Cout,
                                                     int M, int N, int K) {
  __shared__ u16 As[64 * 64];
  __shared__ u16 Bs[64 * 64];
  const int tid = threadIdx.x;
  const int wave = tid >> 6, lane = tid & 63;
  const int g = lane >> 4, li = lane & 15;
  const int wr = wave >> 1, wc = wave & 1;
  const int m0 = blockIdx.y * 64, n0 = blockIdx.x * 64;
  f32x4 acc[2][2];
  f32x4 zz = {0.f, 0.f, 0.f, 0.f};
#pragma unroll
  for (int i = 0; i < 2; ++i)
#pragma unroll
    for (int j = 0; j < 2; ++j) acc[i][j] = zz;

  const int o0 = tid * 16, o1 = o0 + 4096;
  const int r0s = o0 >> 7, s0 = (o0 >> 4) & 7;
  const int r1s = o1 >> 7, s1 = (o1 >> 4) & 7;
  const size_t a0off = (size_t)(m0 + r0s) * K + ((s0 ^ (r0s & 7)) << 3);
  const size_t a1off = (size_t)(m0 + r1s) * K + ((s1 ^ (r1s & 7)) << 3);
  const size_t b0off = (size_t)(n0 + r0s) * K + ((s0 ^ (r0s & 7)) << 3);
  const size_t b1off = (size_t)(n0 + r1s) * K + ((s1 ^ (r1s & 7)) << 3);

  for (int k0 = 0; k0 < K; k0 += 64) {
    uint4 ra0 = *(const uint4*)(A + a0off + k0);
    uint4 ra1 = *(const uint4*)(A + a1off + k0);
    uint4 rb0 = *(const uint4*)(Bt + b0off + k0);
    uint4 rb1 = *(const uint4*)(Bt + b1off + k0);
    __syncthreads();
    *(uint4*)((char*)As + o0) = ra0;
    *(uint4*)((char*)As + o1) = ra1;
    *(uint4*)((char*)Bs + o0) = rb0;
    *(uint4*)((char*)Bs + o1) = rb1;
    __syncthreads();
#pragma unroll
    for (int ko = 0; ko < 2; ++ko) {
      bf16x8 af[2], bfr[2];
#pragma unroll
      for (int mi = 0; mi < 2; ++mi) {
        const int row = wr * 32 + mi * 16 + li;
        const int sl = (ko * 4 + g) ^ (row & 7);
        af[mi] = *(const bf16x8*)((const char*)As + row * 128 + sl * 16);
      }
#pragma unroll
      for (int ni = 0; ni < 2; ++ni) {
        const int row = wc * 32 + ni * 16 + li;
        const int sl = (ko * 4 + g) ^ (row & 7);
        bfr[ni] = *(const bf16x8*)((const char*)Bs + row * 128 + sl * 16);
      }
#pragma unroll
      for (int mi = 0; mi < 2; ++mi)
#pragma unroll
        for (int ni = 0; ni < 2; ++ni)
          acc[mi][ni] = __builtin_amdgcn_mfma_f32_16x16x32_bf16(af[mi], bfr[ni], acc[mi][ni], 0, 0, 0);
    }
  }
#pragma unroll
  for (int ni = 0; ni < 2; ++ni) {
    const int col = n0 + wc * 32 + ni * 16 + li;
    const float bb = BIAS ? bias[col] : 0.f;
#pragma unroll
    for (int mi = 0; mi < 2; ++mi) {
#pragma unroll
      for (int r = 0; r < 4; ++r) {
        const int row = m0 + wr * 32 + mi * 16 + g * 4 + r;
        float v = acc[mi][ni][r] + bb;
        if (ACT) v = gelu_f(v);
        if (OUT_BF16) ((u16*)Cout)[(size_t)row * N + col] = f2bf(v);
        else ((float*)Cout)[(size_t)row * N + col] = v;
      }
    }
  }
}

// ================= dec3 + combine fused =================
__global__ __launch_bounds__(256) void dec3_combine_kernel(const u16* __restrict__ A,
                                                           const u16* __restrict__ Bt,
                                                           const float* __restrict__ bias,
                                                           const float* __restrict__ wtsb,
                                                           float* __restrict__ out,
                                                           int M, int N, int K) {
  __shared__ u16 As[64 * 64];
  __shared__ u16 Bs[64 * 64];
  const int tid = threadIdx.x;
  const int wave = tid >> 6, lane = tid & 63;
  const int g = lane >> 4, li = lane & 15;
  const int wr = wave >> 1, wc = wave & 1;
  const int m0 = blockIdx.y * 64, n0 = blockIdx.x * 64;
  f32x4 acc[2][2];
  f32x4 zz = {0.f, 0.f, 0.f, 0.f};
#pragma unroll
  for (int i = 0; i < 2; ++i)
#pragma unroll
    for (int j = 0; j < 2; ++j) acc[i][j] = zz;

  const int o0 = tid * 16, o1 = o0 + 4096;
  const int r0s = o0 >> 7, s0 = (o0 >> 4) & 7;
  const int r1s = o1 >> 7, s1 = (o1 >> 4) & 7;
  const size_t a0off = (size_t)(m0 + r0s) * K + ((s0 ^ (r0s & 7)) << 3);
  const size_t a1off = (size_t)(m0 + r1s) * K + ((s1 ^ (r1s & 7)) << 3);
  const size_t b0off = (size_t)(n0 + r0s) * K + ((s0 ^ (r0s & 7)) << 3);
  const size_t b1off = (size_t)(n0 + r1s) * K + ((s1 ^ (r1s & 7)) << 3);

  for (int k0 = 0; k0 < K; k0 += 64) {
    uint4 ra0 = *(const uint4*)(A + a0off + k0);
    uint4 ra1 = *(const uint4*)(A + a1off + k0);
    uint4 rb0 = *(const uint4*)(Bt + b0off + k0);
    uint4 rb1 = *(const uint4*)(Bt + b1off + k0);
    __syncthreads();
    *(uint4*)((char*)As + o0) = ra0;
    *(uint4*)((char*)As + o1) = ra1;
    *(uint4*)((char*)Bs + o0) = rb0;
    *(uint4*)((char*)Bs + o1) = rb1;
    __syncthreads();
#pragma unroll
    for (int ko = 0; ko < 2; ++ko) {
      bf16x8 af[2], bfr[2];
#pragma unroll
      for (int mi = 0; mi < 2; ++mi) {
        const int row = wr * 32 + mi * 16 + li;
        const int sl = (ko * 4 + g) ^ (row & 7);
        af[mi] = *(const bf16x8*)((const char*)As + row * 128 + sl * 16);
      }
#pragma unroll
      for (int ni = 0; ni < 2; ++ni) {
        const int row = wc * 32 + ni * 16 + li;
        const int sl = (ko * 4 + g) ^ (row & 7);
        bfr[ni] = *(const bf16x8*)((const char*)Bs + row * 128 + sl * 16);
      }
#pragma unroll
      for (int mi = 0; mi < 2; ++mi)
#pragma unroll
        for (int ni = 0; ni < 2; ++ni)
          acc[mi][ni] = __builtin_amdgcn_mfma_f32_16x16x32_bf16(af[mi], bfr[ni], acc[mi][ni], 0, 0, 0);
    }
  }
#pragma unroll
  for (int mi = 0; mi < 2; ++mi) {
    const int R16 = m0 + wr * 32 + mi * 16;
    const int qb = (R16 >> 3) + (g >> 1);
    const float4 wv = *(const float4*)(wtsb + qb * 8 + (g & 1) * 4);
#pragma unroll
    for (int ni = 0; ni < 2; ++ni) {
      const int col = n0 + wc * 32 + ni * 16 + li;
      const float bb = bias[col];
      float p = (acc[mi][ni][0] + bb) * wv.x;
      p = fmaf(acc[mi][ni][1] + bb, wv.y, p);
      p = fmaf(acc[mi][ni][2] + bb, wv.z, p);
      p = fmaf(acc[mi][ni][3] + bb, wv.w, p);
      p += __shfl_xor(p, 16, 64);
      if ((g & 1) == 0) out[(size_t)qb * 1024 + col] = p;
    }
  }
}

// ================= decoder layer 1, MFMA (fused gather) =================
__global__ __launch_bounds__(256) void dec1_mfma_kernel(const u16* __restrict__ kbf,
                                                        const int* __restrict__ idxb,
                                                        const float* __restrict__ h1c,
                                                        const u16* __restrict__ w1kt,
                                                        const float* __restrict__ db1,
                                                        u16* __restrict__ h1d) {
  __shared__ u16 As[64 * 64];
  __shared__ u16 Bs[64 * 64];
  const int tid = threadIdx.x;
  const int wave = tid >> 6, lane = tid & 63;
  const int g = lane >> 4, li = lane & 15;
  const int wr = wave >> 1, wc = wave & 1;
  const int r0 = blockIdx.y * 64, c0 = blockIdx.x * 64;
  {
    const int o0 = tid * 16, o1 = o0 + 4096;
    const int ra = o0 >> 7, sa = (o0 >> 4) & 7;
    const int rb = o1 >> 7, sb = (o1 >> 4) & 7;
    const int ia = idxb[r0 + ra], ib = idxb[r0 + rb];
    uint4 va = *(const uint4*)(kbf + (size_t)ia * 64 + ((sa ^ (ra & 7)) << 3));
    uint4 vb = *(const uint4*)(kbf + (size_t)ib * 64 + ((sb ^ (rb & 7)) << 3));
    uint4 wa = *(const uint4*)(w1kt + (size_t)(c0 + ra) * 64 + ((sa ^ (ra & 7)) << 3));
    uint4 wb = *(const uint4*)(w1kt + (size_t)(c0 + rb) * 64 + ((sb ^ (rb & 7)) << 3));
    *(uint4*)((char*)As + o0) = va;
    *(uint4*)((char*)As + o1) = vb;
    *(uint4*)((char*)Bs + o0) = wa;
    *(uint4*)((char*)Bs + o1) = wb;
  }
  __syncthreads();
  f32x4 acc[2][2];
  f32x4 zz = {0.f, 0.f, 0.f, 0.f};
#pragma unroll
  for (int i = 0; i < 2; ++i)
#pragma unroll
    for (int j = 0; j < 2; ++j) acc[i][j] = zz;
#pragma unroll
  for (int ko = 0; ko < 2; ++ko) {
    bf16x8 af[2], bfr[2];
#pragma unroll
    for (int mi = 0; mi < 2; ++mi) {
      const int row = wr * 32 + mi * 16 + li;
      const int sl = (ko * 4 + g) ^ (row & 7);
      af[mi] = *(const bf16x8*)((const char*)As + row * 128 + sl * 16);
    }
#pragma unroll
    for (int ni = 0; ni < 2; ++ni) {
      const int row = wc * 32 + ni * 16 + li;
      const int sl = (ko * 4 + g) ^ (row & 7);
      bfr[ni] = *(const bf16x8*)((const char*)Bs + row * 128 + sl * 16);
    }
#pragma unroll
    for (int mi = 0; mi < 2; ++mi)
#pragma unroll
      for (int ni = 0; ni < 2; ++ni)
        acc[mi][ni] = __builtin_amdgcn_mfma_f32_16x16x32_bf16(af[mi], bfr[ni], acc[mi][ni], 0, 0, 0);
  }
#pragma unroll
  for (int ni = 0; ni < 2; ++ni) {
    const int col = c0 + wc * 32 + ni * 16 + li;
    const float bb = db1[col];
#pragma unroll
    for (int mi = 0; mi < 2; ++mi) {
      const int rowb = r0 + wr * 32 + mi * 16 + g * 4;
      const float hv = h1c[(size_t)(rowb >> 3) * 256 + col];
#pragma unroll
      for (int r = 0; r < 4; ++r) {
        float v = acc[mi][ni][r] + hv + bb;
        h1d[(size_t)(rowb + r) * 256 + col] = f2bf(gelu_f(v));
      }
    }
  }
}

// ================= pass A: per-(chunk, query) min; K-fragments hoisted to registers =================
__global__ __launch_bounds__(256) void passA_kernel(const u16* __restrict__ qbf,
                                                    const u16* __restrict__ kbf,
                                                    const float* __restrict__ knorm,
                                                    float* __restrict__ cminT,
                                                    float* __restrict__ cminR) {
  __shared__ u16 Ks[256 * 64];  // 32 KB, XOR-swizzled
  __shared__ float Kn[256];
  const int c = blockIdx.x;
  const int tid = threadIdx.x, wave = tid >> 6, lane = tid & 63;
  const int g = lane >> 4, qi = lane & 15;
#pragma unroll
  for (int r = 0; r < 8; ++r) {
    const int o = tid * 16 + r * 4096;
    const int row = o >> 7, sl = (o >> 4) & 7;
    *(uint4*)((char*)Ks + o) =
        *(const uint4*)(kbf + ((size_t)c * 256 + row) * 64 + ((sl ^ (row & 7)) << 3));
  }
  if (tid < 64) *(float4*)(Kn + tid * 4) = *(const float4*)(knorm + c * 256 + tid * 4);
  __syncthreads();
  const int sl0 = (g ^ (qi & 7)) * 16, sl1 = ((g + 4) ^ (qi & 7)) * 16;
  bf16x8 ka[16], kb[16];
#pragma unroll
  for (int t = 0; t < 16; ++t) {
    const int rb = (t * 16 + qi) * 128;
    ka[t] = *(const bf16x8*)((const char*)Ks + rb + sl0);
    kb[t] = *(const bf16x8*)((const char*)Ks + rb + sl1);
  }
  for (int it = 0; it < 8; ++it) {
    const int q = (wave * 8 + it) * 16 + qi;
    const bf16x8 b0 = *(const bf16x8*)(qbf + (size_t)q * 64 + g * 8);
    const bf16x8 b1 = *(const bf16x8*)(qbf + (size_t)q * 64 + 32 + g * 8);
    float m = 3.4e38f;
#pragma unroll
    for (int t = 0; t < 16; ++t) {
      f32x4 zz = {0.f, 0.f, 0.f, 0.f};
      f32x4 acc = __builtin_amdgcn_mfma_f32_16x16x32_bf16(ka[t], b0, zz, 0, 0, 0);
      acc = __builtin_amdgcn_mfma_f32_16x16x32_bf16(kb[t], b1, acc, 0, 0, 0);
      const float4 kn = *(const float4*)(&Kn[t * 16 + g * 4]);
      m = fminf(m, fmaf(-2.f, acc[0], kn.x));
      m = fminf(m, fmaf(-2.f, acc[1], kn.y));
      m = fminf(m, fmaf(-2.f, acc[2], kn.z));
      m = fminf(m, fmaf(-2.f, acc[3], kn.w));
    }
    m = fminf(m, __shfl_xor(m, 16, 64));
    m = fminf(m, __shfl_xor(m, 32, 64));
    if (lane < 16) {
      cminT[(size_t)c * 512 + q] = m;
      cminR[(size_t)q * 392 + c] = m;
    }
  }
}

// ================= tau: per query, 8th-smallest chunk-min + margin =================
__global__ __launch_bounds__(256) void tau_kernel(const float* __restrict__ cminR,
                                                  float* __restrict__ tau) {
  const int wave = threadIdx.x >> 6, lane = threadIdx.x & 63;
  const int q = blockIdx.x * 4 + wave;
  const float* cp = cminR + (size_t)q * 392;
  u64 t[8];
#pragma unroll
  for (int i = 0; i < 8; ++i) t[i] = ~0ull;
  for (int i = lane; i < 392; i += 64)
    insert8(t, ((u64)__float_as_uint(cp[i]) << 32) | (unsigned)i);
#pragma unroll
  for (int m = 1; m < 64; m <<= 1) {
    u64 o[8];
#pragma unroll
    for (int i = 0; i < 8; ++i) o[i] = shflx64(t[i], m);
    take8(t, o);
  }
  if (lane == 0)
    tau[q] = __uint_as_float((unsigned)(t[7] >> 32)) + 0.02f;  // >= exact-d8 (bf16 err ~2e-3 << 0.02)
}

// ================= pass B: (chunk, 64-query slice); early-exit before staging =================
__global__ __launch_bounds__(256) void passB_kernel(const u16* __restrict__ qbf,
                                                    const u16* __restrict__ kbf,
                                                    const float* __restrict__ knorm,
                                                    const float* __restrict__ cminT,
                                                    const float* __restrict__ tau,
                                                    int* __restrict__ ccnt,
                                                    int* __restrict__ clist) {
  __shared__ u16 Ks[256 * 64];        // 32 KB
  __shared__ float Kn[256];
  __shared__ unsigned short qlist[64];
  __shared__ unsigned acc_pk[4096];   // 16 KB accept staging
  __shared__ int nql, acc_n;
  const int c = blockIdx.x;
  const int qs0 = blockIdx.y * 64;
  const int tid = threadIdx.x, wave = tid >> 6, lane = tid & 63;
  const int g = lane >> 4, qi = lane & 15;
  if (tid == 0) { nql = 0; acc_n = 0; }
  __syncthreads();
  if (tid < 64) {
    const int q = qs0 + tid;
    if (cminT[(size_t)c * 512 + q] <= tau[q]) {  // coalesced 64-float qualify read
      int p = atomicAdd(&nql, 1);
      qlist[p] = (unsigned short)q;
    }
  }
  __syncthreads();
  const int nq = nql;
  if (nq == 0) return;  // uniform: skip staging entirely
#pragma unroll
  for (int r = 0; r < 8; ++r) {
    const int o = tid * 16 + r * 4096;
    const int row = o >> 7, sl = (o >> 4) & 7;
    *(uint4*)((char*)Ks + o) =
        *(const uint4*)(kbf + ((size_t)c * 256 + row) * 64 + ((sl ^ (row & 7)) << 3));
  }
  if (tid < 64) *(float4*)(Kn + tid * 4) = *(const float4*)(knorm + c * 256 + tid * 4);
  __syncthreads();
  const int sl0 = (g ^ (qi & 7)) * 16, sl1 = ((g + 4) ^ (qi & 7)) * 16;
  const float NINF = __uint_as_float(0xff800000u);
  for (int grp = wave; grp * 16 < nq; grp += 4) {
    const int qx = grp * 16 + qi;
    const int valid = qx < nq;
    const int q = valid ? (int)qlist[qx] : 0;
    const float thr = valid ? tau[q] : NINF;
    const bf16x8 b0 = *(const bf16x8*)(qbf + (size_t)q * 64 + g * 8);
    const bf16x8 b1 = *(const bf16x8*)(qbf + (size_t)q * 64 + 32 + g * 8);
#pragma unroll
    for (int t = 0; t < 16; ++t) {
      const int rb = (t * 16 + qi) * 128;
      bf16x8 a0 = *(const bf16x8*)((const char*)Ks + rb + sl0);
      bf16x8 a1 = *(const bf16x8*)((const char*)Ks + rb + sl1);
      f32x4 zz = {0.f, 0.f, 0.f, 0.f};
      f32x4 acc = __builtin_amdgcn_mfma_f32_16x16x32_bf16(a0, b0, zz, 0, 0, 0);
      acc = __builtin_amdgcn_mfma_f32_16x16x32_bf16(a1, b1, acc, 0, 0, 0);
#pragma unroll
      for (int r = 0; r < 4; ++r) {
        const float s = fmaf(-2.f, acc[r], Kn[t * 16 + g * 4 + r]);
        if (s <= thr) {  // LDS-stage the accept
          int p = atomicAdd(&acc_n, 1);
          if (p < 4096) {
            acc_pk[p] = ((unsigned)q << 17) | (unsigned)(c * 256 + t * 16 + g * 4 + r);
          } else {  // overflow fallback: direct, correct
            int pos = atomicAdd(&ccnt[q * 16], 1);
            if (pos < 128) clist[q * 128 + pos] = c * 256 + t * 16 + g * 4 + r;
          }
        }
      }
    }
  }
  __syncthreads();
  int na = acc_n;
  if (na > 4096) na = 4096;
  for (int i = tid; i < na; i += 256) {
    const unsigned pk = acc_pk[i];
    const int q = (int)(pk >> 17);
    const int key = (int)(pk & 0x1FFFFu);
    int pos = atomicAdd(&ccnt[q * 16], 1);
    if (pos < 128) clist[q * 128 + pos] = key;
  }
}

// ================= exact fp32 re-rank of survivors -> final top-8 =================
__global__ __launch_bounds__(256) void rerank_kernel(const int* __restrict__ clist,
                                                     const int* __restrict__ ccnt,
                                                     const float* __restrict__ qc,
                                                     const float* __restrict__ keys,
                                                     const float* __restrict__ knorm,
                                                     int* __restrict__ idxb,
                                                     float* __restrict__ wtsb,
                                                     float* __restrict__ conf) {
  const int sub = threadIdx.x >> 6, lane = threadIdx.x & 63;
  const int q = blockIdx.x * 4 + sub;
  __shared__ float qs[4][64];
  if (lane < 16) *(float4*)(&qs[sub][lane * 4]) = ((const float4*)(qc + (size_t)q * 64))[lane];
  __syncthreads();
  float qn = 0.f;
#pragma unroll
  for (int u = 0; u < 16; ++u) {
    float4 v = *(const float4*)(&qs[sub][u * 4]);
    qn = fmaf(v.x, v.x, fmaf(v.y, v.y, fmaf(v.z, v.z, fmaf(v.w, v.w, qn))));
  }
  int n = ccnt[q * 16];
  if (n > 128) n = 128;
  u64 t[8];
#pragma unroll
  for (int i = 0; i < 8; ++i) t[i] = ~0ull;
  for (int ci = lane; ci < n; ci += 64) {
    const int idx = clist[q * 128 + ci];
    const float4* kr = (const float4*)(keys + (size_t)idx * 64);
    float a0 = 0.f, a1 = 0.f, a2 = 0.f, a3 = 0.f;
#pragma unroll
    for (int u = 0; u < 16; u += 4) {
      float4 k0 = kr[u], k1 = kr[u + 1], k2 = kr[u + 2], k3 = kr[u + 3];
      float4 q0 = *(const float4*)(&qs[sub][u * 4]), q1 = *(const float4*)(&qs[sub][u * 4 + 4]);
      float4 q2 = *(const float4*)(&qs[sub][u * 4 + 8]), q3 = *(const float4*)(&qs[sub][u * 4 + 12]);
      a0 = fmaf(q0.x, k0.x, a0); a0 = fmaf(q0.y, k0.y, a0); a0 = fmaf(q0.z, k0.z, a0); a0 = fmaf(q0.w, k0.w, a0);
      a1 = fmaf(q1.x, k1.x, a1); a1 = fmaf(q1.y, k1.y, a1); a1 = fmaf(q1.z, k1.z, a1); a1 = fmaf(q1.w, k1.w, a1);
      a2 = fmaf(q2.x, k2.x, a2); a2 = fmaf(q2.y, k2.y, a2); a2 = fmaf(q2.z, k2.z, a2); a2 = fmaf(q2.w, k2.w, a2);
      a3 = fmaf(q3.x, k3.x, a3); a3 = fmaf(q3.y, k3.y, a3); a3 = fmaf(q3.z, k3.z, a3); a3 = fmaf(q3.w, k3.w, a3);
    }
    float dot = (a0 + a1) + (a2 + a3);
    float d2 = fmaf(-2.f, dot, qn + knorm[idx]);
    d2 = fmaxf(d2, 0.f);
    insert8(t, ((u64)__float_as_uint(d2) << 32) | (unsigned)idx);
  }
#pragma unroll
  for (int m = 1; m < 64; m <<= 1) {
    u64 o[8];
#pragma unroll
    for (int i = 0; i < 8; ++i) o[i] = shflx64(t[i], m);
    take8(t, o);
  }
  if (lane == 0) {
    float w8[8], s = 0.f;
#pragma unroll
    for (int i = 0; i < 8; ++i) {
      float d = __uint_as_float((unsigned)(t[i] >> 32));
      w8[i] = 1.f / (d + 1e-6f);
      s += w8[i];
    }
    conf[q] = w8[0];
#pragma unroll
    for (int i = 0; i < 8; ++i) {
      idxb[q * 8 + i] = (int)(unsigned)(t[i] & 0xffffffffull);
      wtsb[q * 8 + i] = w8[i] / s;
    }
  }
}

extern "C" void kernel_launch(void* const* d_in, const int* in_sizes, int n_in,
                              void* d_out, int out_size, void* d_ws, size_t ws_size,
                              hipStream_t stream) {
  const float* query   = (const float*)d_in[0];
  const float* context = (const float*)d_in[1];
  const float* keys    = (const float*)d_in[2];
  const float* ew1 = (const float*)d_in[3];
  const float* eb1 = (const float*)d_in[4];
  const float* ew2 = (const float*)d_in[5];
  const float* eb2 = (const float*)d_in[6];
  const float* ew3 = (const float*)d_in[7];
  const float* eb3 = (const float*)d_in[8];
  const float* dw1 = (const float*)d_in[9];
  const float* db1 = (const float*)d_in[10];
  const float* dw2 = (const float*)d_in[11];
  const float* db2 = (const float*)d_in[12];
  const float* dw3 = (const float*)d_in[13];
  const float* db3 = (const float*)d_in[14];
  float* out = (float*)d_out;

  char* ws = (char*)d_ws;
  float* qc    = (float*)(ws + 0);          // 131072
  float* knorm = (float*)(ws + 131072);     // 100352*4 = 401408
  u16*   qbf   = (u16*)  (ws + 532480);     // 65536
  int*   idxb  = (int*)  (ws + 1384448);    // 16384
  float* wtsb  = (float*)(ws + 1400832);    // 16384
  float* h1c   = (float*)(ws + 1417216);    // 524288
  u16*   kbf   = (u16*)  (ws + 1941504);    // 100352*64*2 = 12845056
  float* cminT = (float*)(ws + 14786560);   // 392*512*4 = 802816
  float* cminR = (float*)(ws + 15589376);   // 512*392*4 = 802816
  float* tau   = (float*)(ws + 16392192);   // 2048
  int*   ccnt  = (int*)  (ws + 16394240);   // 512*16*4 = 32768 (64B-padded counters)
  int*   clist = (int*)  (ws + 16427008);   // 512*128*4 = 262144
  u16*   h1d   = (u16*)  (ws + 16689152);   // 2097152
  u16*   h2d   = (u16*)  (ws + 18786304);   // 4194304
  u16*   w2t   = (u16*)  (ws + 22980608);   // 262144
  u16*   w3t   = (u16*)  (ws + 23242752);   // 1048576
  u16*   w1kt  = (u16*)  (ws + 25864192);   // 32768
  float* eh1f  = (float*)(ws + 25896960);   // 512*256*4 = 524288 (end 26421248)

  // 1. fused preprocessing + h1c (fp32) + enc1 (all independent of each other)
  prep_kernel<<<dim3(2073), dim3(256), 0, stream>>>(keys, knorm, kbf, dw1, w1kt,
                                                    dw2, w2t, dw3, w3t, context, h1c,
                                                    ccnt, query, ew1, eb1, eh1f);

  // 2. enc2+enc3 fused (bit-identical chain; emits qc + qbf)
  enc23_kernel<<<dim3(128), dim3(512), 0, stream>>>(eh1f, ew2, eb2, ew3, eb3, qc, qbf);

  // 3-6. selection: chunk-min scan -> tau -> sliced filtered collect -> exact rerank
  passA_kernel<<<dim3(392), dim3(256), 0, stream>>>(qbf, kbf, knorm, cminT, cminR);
  tau_kernel<<<dim3(128), dim3(256), 0, stream>>>(cminR, tau);
  passB_kernel<<<dim3(392, 8), dim3(256), 0, stream>>>(qbf, kbf, knorm, cminT, tau, ccnt, clist);
  rerank_kernel<<<dim3(128), dim3(256), 0, stream>>>(clist, ccnt, qc, keys, knorm,
                                                     idxb, wtsb, out + 524288);

  // 7-9. decoder
  dec1_mfma_kernel<<<dim3(4, 64), dim3(256), 0, stream>>>(kbf, idxb, h1c, w1kt, db1, h1d);
  mfma64_kernel<1, 1, 1><<<dim3(8, 64), dim3(256), 0, stream>>>(h1d, w2t, db2, h2d, 4096, 512, 256);
  dec3_combine_kernel<<<dim3(16, 64), dim3(256), 0, stream>>>(h2d, w3t, db3, wtsb, out,
                                                              4096, 1024, 512);
}